// Round 4
// baseline (390.569 us; speedup 1.0000x reference)
//
#include <hip/hip_runtime.h>

typedef __bf16 bf16x8 __attribute__((ext_vector_type(8)));
typedef float f32x4 __attribute__((ext_vector_type(4)));

static __device__ __forceinline__ unsigned short f2bf(float f) {
    unsigned u = __builtin_bit_cast(unsigned, f);
    u += 0x7FFFu + ((u >> 16) & 1u);
    return (unsigned short)(u >> 16);
}
static __device__ __forceinline__ float bf2f(unsigned short h) {
    return __builtin_bit_cast(float, ((unsigned)h) << 16);
}

// async 16B global->LDS (linear LDS dest: wave-uniform base + lane*16)
#define GLOAD_LDS16(g, l)                                              \
    __builtin_amdgcn_global_load_lds(                                  \
        (const __attribute__((address_space(1))) unsigned int*)(g),    \
        (__attribute__((address_space(3))) unsigned int*)(l), 16, 0, 0)

// ---------------------------------------------------------------- tiny utils
__global__ __launch_bounds__(256) void rgcn_zero(unsigned* __restrict__ p, int n) {
    int i = blockIdx.x * 256 + threadIdx.x;
    if (i < n) p[i] = 0;
}

// histogram of dst
__global__ __launch_bounds__(256) void rgcn_hist(const int* __restrict__ ei,
                                                 unsigned* __restrict__ cnt, int E) {
    int e = blockIdx.x * 256 + threadIdx.x;
    if (e < E) atomicAdd(&cnt[ei[E + e]], 1u);
}

// ---------------- hierarchical exclusive scan (3 kernels) ----------------
__global__ __launch_bounds__(1024) void rgcn_scan1(const unsigned* __restrict__ cnt,
                                                   unsigned* __restrict__ off,
                                                   unsigned* __restrict__ bsum, int n) {
    __shared__ unsigned ws[16];
    const int t = threadIdx.x, lane = t & 63, wv = t >> 6;
    int i = blockIdx.x * 1024 + t;
    unsigned v = (i < n) ? cnt[i] : 0;
    unsigned s = v;
    #pragma unroll
    for (int d = 1; d < 64; d <<= 1) {
        unsigned u = __shfl_up(s, d, 64);
        if (lane >= d) s += u;
    }
    if (lane == 63) ws[wv] = s;
    __syncthreads();
    if (wv == 0) {
        unsigned b = (lane < 16) ? ws[lane] : 0;
        unsigned sb = b;
        #pragma unroll
        for (int d = 1; d < 16; d <<= 1) {
            unsigned u = __shfl_up(sb, d, 64);
            if (lane >= d) sb += u;
        }
        if (lane < 16) ws[lane] = sb - b;          // exclusive wave prefix
        if (lane == 15) bsum[blockIdx.x] = sb;     // block total
    }
    __syncthreads();
    if (i < n) off[i] = ws[wv] + (s - v);
}

__global__ __launch_bounds__(64) void rgcn_scan2(unsigned* __restrict__ bsum,
                                                 unsigned* __restrict__ bsumo,
                                                 unsigned* __restrict__ off, int nb, int n) {
    const int lane = threadIdx.x & 63;
    unsigned b = (lane < nb) ? bsum[lane] : 0;
    unsigned s = b;
    #pragma unroll
    for (int d = 1; d < 64; d <<= 1) {
        unsigned u = __shfl_up(s, d, 64);
        if (lane >= d) s += u;
    }
    if (lane < nb) bsumo[lane] = s - b;
    if (lane == 63) off[n] = s;
}

__global__ __launch_bounds__(256) void rgcn_scan3(unsigned* __restrict__ off,
                                                  const unsigned* __restrict__ bsumo,
                                                  unsigned* __restrict__ cur, int n) {
    int i = blockIdx.x * 256 + threadIdx.x;
    if (i < n) {
        unsigned v = off[i] + bsumo[i >> 10];
        off[i] = v;
        cur[i] = v;
    }
}

// scatter packed records (src | rel<<16) into dst-sorted order
__global__ __launch_bounds__(256) void rgcn_scatter(const int* __restrict__ ei,
                                                    const int* __restrict__ et,
                                                    unsigned* __restrict__ cur,
                                                    unsigned* __restrict__ recs, int E) {
    int e = blockIdx.x * 256 + threadIdx.x;
    if (e < E) {
        int dst = ei[E + e];
        unsigned p = atomicAdd(&cur[dst], 1u);
        recs[p] = (unsigned)ei[e] | ((unsigned)et[e] << 16);
    }
}

// write bf16 x into Zcat columns 2048..2303 (one wave per node row)
__global__ __launch_bounds__(256) void rgcn_cvt(const float* __restrict__ x,
                                                unsigned short* __restrict__ Z, int M) {
    int w = (blockIdx.x * 256 + threadIdx.x) >> 6;
    int lane = threadIdx.x & 63;
    if (w >= M) return;
    float4 v = *(const float4*)(x + (size_t)w * 256 + lane * 4);
    ushort4 o;
    o.x = f2bf(v.x); o.y = f2bf(v.y); o.z = f2bf(v.z); o.w = f2bf(v.w);
    *(ushort4*)(Z + (size_t)w * 2304 + 2048 + lane * 4) = o;
}

// wbT[n][kc]: kc<2048 -> weight[kc>>8][kc&255][n]; else loop_w[kc-2048][n]; both * sqrt(0.5)
__global__ __launch_bounds__(256) void rgcn_wbt(const float* __restrict__ w,
                                                const float* __restrict__ lw,
                                                unsigned short* __restrict__ wbT) {
    int kc = blockIdx.x * 256 + threadIdx.x;   // 0..2303
    int n  = blockIdx.y;                       // 0..255
    if (kc >= 2304) return;
    float v;
    if (kc < 2048) {
        int r = kc >> 8, k = kc & 255;
        v = w[((size_t)r * 256 + k) * 256 + n];
    } else {
        v = lw[(size_t)(kc - 2048) * 256 + n];
    }
    wbT[(size_t)n * 2304 + kc] = f2bf(v * 0.70710678118654752f);
}

// ---------------------------------------------------------------- aggregation
// one wave per dst node: sum bf16 x rows per relation into registers; write 8 Z
// relation rows with NON-TEMPORAL stores (keep the 25.6MB x gather region cached).
__global__ __launch_bounds__(256) void rgcn_agg(const unsigned* __restrict__ recs,
                                                const unsigned* __restrict__ off,
                                                unsigned short* __restrict__ Z, int M) {
    int w = (blockIdx.x * 256 + threadIdx.x) >> 6;
    int lane = threadIdx.x & 63;
    if (w >= M) return;
    unsigned o0 = off[w], o1 = off[w + 1];
    f32x4 a0 = {}, a1 = {}, a2 = {}, a3 = {}, a4 = {}, a5 = {}, a6 = {}, a7 = {};

    // src fits in 16 bits (M = 50000 < 65536)
#define LOADF(rec, fv)                                                                 \
    {                                                                                  \
        const ushort4 v_ = *(const ushort4*)(Z + (size_t)((rec) & 0xFFFFu) * 2304 +    \
                                             2048 + lane * 4);                         \
        fv[0] = bf2f(v_.x); fv[1] = bf2f(v_.y); fv[2] = bf2f(v_.z); fv[3] = bf2f(v_.w);\
    }
#define ACCUM(rec, fv)                                                                 \
    switch ((rec) >> 16) {                                                             \
        case 0: a0 += fv; break; case 1: a1 += fv; break;                              \
        case 2: a2 += fv; break; case 3: a3 += fv; break;                              \
        case 4: a4 += fv; break; case 5: a5 += fv; break;                              \
        case 6: a6 += fv; break; default: a7 += fv; break;                             \
    }

    unsigned i = o0;
    for (; i + 8 <= o1; i += 8) {   // 8-wide gather ILP
        unsigned r0 = recs[i],     r1 = recs[i + 1], r2 = recs[i + 2], r3 = recs[i + 3];
        unsigned r4 = recs[i + 4], r5 = recs[i + 5], r6 = recs[i + 6], r7 = recs[i + 7];
        f32x4 f0, f1, f2, f3, f4, f5, f6, f7;
        LOADF(r0, f0); LOADF(r1, f1); LOADF(r2, f2); LOADF(r3, f3);
        LOADF(r4, f4); LOADF(r5, f5); LOADF(r6, f6); LOADF(r7, f7);
        ACCUM(r0, f0); ACCUM(r1, f1); ACCUM(r2, f2); ACCUM(r3, f3);
        ACCUM(r4, f4); ACCUM(r5, f5); ACCUM(r6, f6); ACCUM(r7, f7);
    }
    for (; i < o1; ++i) {
        unsigned r0 = recs[i];
        f32x4 f0;
        LOADF(r0, f0);
        ACCUM(r0, f0);
    }
#undef LOADF
#undef ACCUM

    unsigned short* zr = Z + (size_t)w * 2304 + lane * 4;
#define ST(rr, ax)                                                                     \
    {                                                                                  \
        unsigned lo_ = (unsigned)f2bf(ax[0]) | ((unsigned)f2bf(ax[1]) << 16);          \
        unsigned hi_ = (unsigned)f2bf(ax[2]) | ((unsigned)f2bf(ax[3]) << 16);          \
        unsigned long long v_ = (unsigned long long)lo_ |                              \
                                ((unsigned long long)hi_ << 32);                       \
        __builtin_nontemporal_store(v_, (unsigned long long*)(zr + rr * 256));         \
    }
    ST(0, a0) ST(1, a1) ST(2, a2) ST(3, a3) ST(4, a4) ST(5, a5) ST(6, a6) ST(7, a7)
#undef ST
}

// ---------------------------------------------------------------- GEMM
// out[M x 256] = Zcat[M x 2304] @ wbT^T + bias
// 128x256 tile (BN covers all of N -> A fetched from HBM exactly once).
// m97 structure: global_load_lds w16, linear LDS dest, XOR-swizzle via
// pre-swizzled global source; swizzled ds_read_b128.
#define BM 128
#define BK 64

__global__ __launch_bounds__(256) void rgcn_gemm(
    const unsigned short* __restrict__ A,    // Zcat [M][2304]
    const unsigned short* __restrict__ Bt,   // wbT  [256][2304]
    float* __restrict__ out,                 // [M][256]
    const float* __restrict__ bias,          // [256]
    int M)
{
    __shared__ char lds[16384 + 32768];   // A 128x64 bf16 + B 256x64 bf16
    char* Ab = lds;
    char* Bb = lds + 16384;

    const int tid  = threadIdx.x;
    const int lane = tid & 63;
    const int wid  = tid >> 6;
    const int wm   = (wid >> 1) * 64;    // 0 / 64
    const int wn   = (wid & 1) * 128;    // 0 / 128
    const int m0   = blockIdx.x * BM;

    f32x4 acc[4][8] = {};

    for (int kt = 0; kt < 2304; kt += BK) {
        __syncthreads();
        // A tile: 4 chunks of 4KB
        #pragma unroll
        for (int it = 0; it < 4; ++it) {
            int o   = it * 4096 + tid * 16;
            int r   = o >> 7;                       // row 0..127
            int scb = (o & 127) ^ ((r & 7) << 4);   // pre-swizzled source col byte
            int ga  = m0 + r; if (ga >= M) ga = M - 1;   // tail clamp (row unused at C-write)
            GLOAD_LDS16((const char*)A + (size_t)ga * 4608 + (size_t)kt * 2 + scb, Ab + o);
        }
        // B tile: 8 chunks of 4KB (rows 0..255)
        #pragma unroll
        for (int it = 0; it < 8; ++it) {
            int o   = it * 4096 + tid * 16;
            int r   = o >> 7;
            int scb = (o & 127) ^ ((r & 7) << 4);
            GLOAD_LDS16((const char*)Bt + (size_t)r * 4608 + (size_t)kt * 2 + scb, Bb + o);
        }
        __syncthreads();   // compiler drains vmcnt before barrier
        #pragma unroll
        for (int kk = 0; kk < 2; ++kk) {
            const int koff = kk * 32 + (lane >> 4) * 8;
            bf16x8 af[4], bfr[8];
            #pragma unroll
            for (int i = 0; i < 4; ++i) {
                int ar = wm + i * 16 + (lane & 15);
                af[i] = *(const bf16x8*)(Ab + ((ar * 128 + koff * 2) ^ ((ar & 7) << 4)));
            }
            #pragma unroll
            for (int j = 0; j < 8; ++j) {
                int br = wn + j * 16 + (lane & 15);
                bfr[j] = *(const bf16x8*)(Bb + ((br * 128 + koff * 2) ^ ((br & 7) << 4)));
            }
            #pragma unroll
            for (int i = 0; i < 4; ++i)
                #pragma unroll
                for (int j = 0; j < 8; ++j)
                    acc[i][j] = __builtin_amdgcn_mfma_f32_16x16x32_bf16(af[i], bfr[j], acc[i][j], 0, 0, 0);
        }
    }

    // D mapping: col=lane&15, row=(lane>>4)*4+reg
    const int col = lane & 15;
    const int r0  = (lane >> 4) * 4;
    #pragma unroll
    for (int i = 0; i < 4; ++i) {
        #pragma unroll
        for (int j = 0; j < 8; ++j) {
            int gn = wn + j * 16 + col;
            float bv = bias[gn];
            #pragma unroll
            for (int rr = 0; rr < 4; ++rr) {
                int gm = m0 + wm + i * 16 + r0 + rr;
                if (gm < M) out[(size_t)gm * 256 + gn] = acc[i][j][rr] + bv;
            }
        }
    }
}

// ---------------------------------------------------------------- launch
extern "C" void kernel_launch(void* const* d_in, const int* in_sizes, int n_in,
                              void* d_out, int out_size, void* d_ws, size_t ws_size,
                              hipStream_t stream) {
    const int*   edge_index = (const int*)d_in[0];   // [2][E]
    const float* x          = (const float*)d_in[1]; // [M][256]
    const int*   edge_type  = (const int*)d_in[2];   // [E]
    const float* weight     = (const float*)d_in[3]; // [8][256][256]
    const float* h_bias     = (const float*)d_in[4]; // [256]
    const float* loop_w     = (const float*)d_in[5]; // [256][256]
    float* out = (float*)d_out;

    const int M = in_sizes[1] / 256;   // 50000
    const int E = in_sizes[2];         // 800000

    // workspace: Zcat 230.4MB | wbT 1.18MB | cnt | off | bsum | bsumo | recs
    char* ws = (char*)d_ws;
    size_t off_b = 0;
    unsigned short* Zcat = (unsigned short*)(ws + off_b);
    off_b += (((size_t)M * 2304 * 2) + 255) & ~(size_t)255;
    unsigned short* wbT = (unsigned short*)(ws + off_b);
    off_b += (((size_t)256 * 2304 * 2) + 255) & ~(size_t)255;
    unsigned* cnt = (unsigned*)(ws + off_b);
    off_b += (((size_t)(M + 1) * 4) + 255) & ~(size_t)255;
    unsigned* off = (unsigned*)(ws + off_b);
    off_b += (((size_t)(M + 1) * 4) + 255) & ~(size_t)255;
    unsigned* bsum = (unsigned*)(ws + off_b);
    off_b += 256;
    unsigned* bsumo = (unsigned*)(ws + off_b);
    off_b += 256;
    unsigned* recs = (unsigned*)(ws + off_b);

    const int nb = (M + 1023) / 1024;   // 49 scan blocks (<= 64)

    // counting sort of edges by dst
    rgcn_zero<<<(M + 255) / 256, 256, 0, stream>>>(cnt, M);
    rgcn_hist<<<(E + 255) / 256, 256, 0, stream>>>(edge_index, cnt, E);
    rgcn_scan1<<<nb, 1024, 0, stream>>>(cnt, off, bsum, M);
    rgcn_scan2<<<1, 64, 0, stream>>>(bsum, bsumo, off, nb, M);
    rgcn_scan3<<<(M + 255) / 256, 256, 0, stream>>>(off, bsumo, cnt, M);
    rgcn_scatter<<<(E + 255) / 256, 256, 0, stream>>>(edge_index, edge_type, cnt, recs, E);

    // bf16 x into Zcat[:, 2048:2304]; weights transposed+scaled
    rgcn_cvt<<<(M + 3) / 4, 256, 0, stream>>>(x, Zcat, M);
    rgcn_wbt<<<dim3(9, 256), 256, 0, stream>>>(weight, loop_w, wbT);

    // per-dst register aggregation -> Zcat[:, 0:2048]
    rgcn_agg<<<(M + 3) / 4, 256, 0, stream>>>(recs, off, Zcat, M);

    // single fused GEMM -> out (BN=256 covers all of N)
    rgcn_gemm<<<(M + BM - 1) / BM, 256, 0, stream>>>(Zcat, wbT, out, h_bias, M);
}

// Round 5
// 359.347 us; speedup vs baseline: 1.0869x; 1.0869x over previous
//
#include <hip/hip_runtime.h>

typedef __bf16 bf16x8 __attribute__((ext_vector_type(8)));
typedef float f32x4 __attribute__((ext_vector_type(4)));

static __device__ __forceinline__ unsigned short f2bf(float f) {
    unsigned u = __builtin_bit_cast(unsigned, f);
    u += 0x7FFFu + ((u >> 16) & 1u);
    return (unsigned short)(u >> 16);
}
static __device__ __forceinline__ float bf2f(unsigned short h) {
    return __builtin_bit_cast(float, ((unsigned)h) << 16);
}

// async 16B global->LDS (linear LDS dest: wave-uniform base + lane*16)
#define GLOAD_LDS16(g, l)                                              \
    __builtin_amdgcn_global_load_lds(                                  \
        (const __attribute__((address_space(1))) unsigned int*)(g),    \
        (__attribute__((address_space(3))) unsigned int*)(l), 16, 0, 0)

// ---------------------------------------------------------------- tiny utils
__global__ __launch_bounds__(256) void rgcn_zero(unsigned* __restrict__ p, int n) {
    int i = blockIdx.x * 256 + threadIdx.x;
    if (i < n) p[i] = 0;
}

// histogram of dst
__global__ __launch_bounds__(256) void rgcn_hist(const int* __restrict__ ei,
                                                 unsigned* __restrict__ cnt, int E) {
    int e = blockIdx.x * 256 + threadIdx.x;
    if (e < E) atomicAdd(&cnt[ei[E + e]], 1u);
}

// ---------------- hierarchical exclusive scan (3 kernels) ----------------
__global__ __launch_bounds__(1024) void rgcn_scan1(const unsigned* __restrict__ cnt,
                                                   unsigned* __restrict__ off,
                                                   unsigned* __restrict__ bsum, int n) {
    __shared__ unsigned ws[16];
    const int t = threadIdx.x, lane = t & 63, wv = t >> 6;
    int i = blockIdx.x * 1024 + t;
    unsigned v = (i < n) ? cnt[i] : 0;
    unsigned s = v;
    #pragma unroll
    for (int d = 1; d < 64; d <<= 1) {
        unsigned u = __shfl_up(s, d, 64);
        if (lane >= d) s += u;
    }
    if (lane == 63) ws[wv] = s;
    __syncthreads();
    if (wv == 0) {
        unsigned b = (lane < 16) ? ws[lane] : 0;
        unsigned sb = b;
        #pragma unroll
        for (int d = 1; d < 16; d <<= 1) {
            unsigned u = __shfl_up(sb, d, 64);
            if (lane >= d) sb += u;
        }
        if (lane < 16) ws[lane] = sb - b;          // exclusive wave prefix
        if (lane == 15) bsum[blockIdx.x] = sb;     // block total
    }
    __syncthreads();
    if (i < n) off[i] = ws[wv] + (s - v);
}

__global__ __launch_bounds__(64) void rgcn_scan2(unsigned* __restrict__ bsum,
                                                 unsigned* __restrict__ bsumo,
                                                 unsigned* __restrict__ off, int nb, int n) {
    const int lane = threadIdx.x & 63;
    unsigned b = (lane < nb) ? bsum[lane] : 0;
    unsigned s = b;
    #pragma unroll
    for (int d = 1; d < 64; d <<= 1) {
        unsigned u = __shfl_up(s, d, 64);
        if (lane >= d) s += u;
    }
    if (lane < nb) bsumo[lane] = s - b;
    if (lane == 63) off[n] = s;
}

__global__ __launch_bounds__(256) void rgcn_scan3(unsigned* __restrict__ off,
                                                  const unsigned* __restrict__ bsumo,
                                                  unsigned* __restrict__ cur, int n) {
    int i = blockIdx.x * 256 + threadIdx.x;
    if (i < n) {
        unsigned v = off[i] + bsumo[i >> 10];
        off[i] = v;
        cur[i] = v;
    }
}

// scatter packed records (src | rel<<16) into dst-sorted order
__global__ __launch_bounds__(256) void rgcn_scatter(const int* __restrict__ ei,
                                                    const int* __restrict__ et,
                                                    unsigned* __restrict__ cur,
                                                    unsigned* __restrict__ recs, int E) {
    int e = blockIdx.x * 256 + threadIdx.x;
    if (e < E) {
        int dst = ei[E + e];
        unsigned p = atomicAdd(&cur[dst], 1u);
        recs[p] = (unsigned)ei[e] | ((unsigned)et[e] << 16);
    }
}

// write bf16 x into Zcat columns 2048..2303 (one wave per node row)
__global__ __launch_bounds__(256) void rgcn_cvt(const float* __restrict__ x,
                                                unsigned short* __restrict__ Z, int M) {
    int w = (blockIdx.x * 256 + threadIdx.x) >> 6;
    int lane = threadIdx.x & 63;
    if (w >= M) return;
    float4 v = *(const float4*)(x + (size_t)w * 256 + lane * 4);
    ushort4 o;
    o.x = f2bf(v.x); o.y = f2bf(v.y); o.z = f2bf(v.z); o.w = f2bf(v.w);
    *(ushort4*)(Z + (size_t)w * 2304 + 2048 + lane * 4) = o;
}

// wbT[n][kc]: kc<2048 -> weight[kc>>8][kc&255][n]; else loop_w[kc-2048][n]; both * sqrt(0.5)
__global__ __launch_bounds__(256) void rgcn_wbt(const float* __restrict__ w,
                                                const float* __restrict__ lw,
                                                unsigned short* __restrict__ wbT) {
    int kc = blockIdx.x * 256 + threadIdx.x;   // 0..2303
    int n  = blockIdx.y;                       // 0..255
    if (kc >= 2304) return;
    float v;
    if (kc < 2048) {
        int r = kc >> 8, k = kc & 255;
        v = w[((size_t)r * 256 + k) * 256 + n];
    } else {
        v = lw[(size_t)(kc - 2048) * 256 + n];
    }
    wbT[(size_t)n * 2304 + kc] = f2bf(v * 0.70710678118654752f);
}

// ---------------------------------------------------------------- aggregation
// one wave per dst node: sum bf16 x rows per relation into registers; write 8 Z rows
__global__ __launch_bounds__(256) void rgcn_agg(const unsigned* __restrict__ recs,
                                                const unsigned* __restrict__ off,
                                                unsigned short* __restrict__ Z, int M) {
    int w = (blockIdx.x * 256 + threadIdx.x) >> 6;
    int lane = threadIdx.x & 63;
    if (w >= M) return;
    unsigned o0 = off[w], o1 = off[w + 1];
    f32x4 a0 = {}, a1 = {}, a2 = {}, a3 = {}, a4 = {}, a5 = {}, a6 = {}, a7 = {};

    // src fits in 16 bits (M = 50000 < 65536)
#define LOADF(rec, fv)                                                                 \
    {                                                                                  \
        const ushort4 v_ = *(const ushort4*)(Z + (size_t)((rec) & 0xFFFFu) * 2304 +    \
                                             2048 + lane * 4);                         \
        fv[0] = bf2f(v_.x); fv[1] = bf2f(v_.y); fv[2] = bf2f(v_.z); fv[3] = bf2f(v_.w);\
    }
#define ACCUM(rec, fv)                                                                 \
    switch ((rec) >> 16) {                                                             \
        case 0: a0 += fv; break; case 1: a1 += fv; break;                              \
        case 2: a2 += fv; break; case 3: a3 += fv; break;                              \
        case 4: a4 += fv; break; case 5: a5 += fv; break;                              \
        case 6: a6 += fv; break; default: a7 += fv; break;                             \
    }

    unsigned i = o0;
    for (; i + 8 <= o1; i += 8) {   // 8-wide gather ILP
        unsigned r0 = recs[i],     r1 = recs[i + 1], r2 = recs[i + 2], r3 = recs[i + 3];
        unsigned r4 = recs[i + 4], r5 = recs[i + 5], r6 = recs[i + 6], r7 = recs[i + 7];
        f32x4 f0, f1, f2, f3, f4, f5, f6, f7;
        LOADF(r0, f0); LOADF(r1, f1); LOADF(r2, f2); LOADF(r3, f3);
        LOADF(r4, f4); LOADF(r5, f5); LOADF(r6, f6); LOADF(r7, f7);
        ACCUM(r0, f0); ACCUM(r1, f1); ACCUM(r2, f2); ACCUM(r3, f3);
        ACCUM(r4, f4); ACCUM(r5, f5); ACCUM(r6, f6); ACCUM(r7, f7);
    }
    for (; i < o1; ++i) {
        unsigned r0 = recs[i];
        f32x4 f0;
        LOADF(r0, f0);
        ACCUM(r0, f0);
    }
#undef LOADF
#undef ACCUM

    unsigned short* zr = Z + (size_t)w * 2304 + lane * 4;
#define ST(rr, ax)                                                                     \
    {                                                                                  \
        ushort4 o_;                                                                    \
        o_.x = f2bf(ax[0]); o_.y = f2bf(ax[1]); o_.z = f2bf(ax[2]); o_.w = f2bf(ax[3]);\
        *(ushort4*)(zr + rr * 256) = o_;                                               \
    }
    ST(0, a0) ST(1, a1) ST(2, a2) ST(3, a3) ST(4, a4) ST(5, a5) ST(6, a6) ST(7, a7)
#undef ST
}

// ---------------------------------------------------------------- GEMM
// out[M x 256] = Zcat[M x 2304] @ wbT^T + bias
// 64x256 tile: A read from HBM exactly once, B (1.15MB) L2-resident.
// 4 waves, each owns 64x64. LDS 40KB -> 4 blocks/CU (~16 waves/CU).
#define BM 64
#define BK 64

__global__ __launch_bounds__(256) void rgcn_gemm(
    const unsigned short* __restrict__ A,    // Zcat [M][2304]
    const unsigned short* __restrict__ Bt,   // wbT  [256][2304]
    float* __restrict__ out,                 // [M][256]
    const float* __restrict__ bias,          // [256]
    int M)
{
    __shared__ char lds[8192 + 32768];   // A 64x64 bf16 + B 256x64 bf16
    char* Ab = lds;
    char* Bb = lds + 8192;

    const int tid  = threadIdx.x;
    const int lane = tid & 63;
    const int wid  = tid >> 6;
    const int wn   = wid * 64;           // wave column offset (0/64/128/192)
    const int m0   = blockIdx.x * BM;

    f32x4 acc[4][4] = {};

    for (int kt = 0; kt < 2304; kt += BK) {
        __syncthreads();
        // A tile: 2 chunks of 4KB (rows 0..63)
        #pragma unroll
        for (int it = 0; it < 2; ++it) {
            int o   = it * 4096 + tid * 16;
            int r   = o >> 7;                       // row 0..63
            int scb = (o & 127) ^ ((r & 7) << 4);   // pre-swizzled source col byte
            int ga  = m0 + r; if (ga >= M) ga = M - 1;   // tail clamp (row unused at C-write)
            GLOAD_LDS16((const char*)A + (size_t)ga * 4608 + (size_t)kt * 2 + scb, Ab + o);
        }
        // B tile: 8 chunks of 4KB (rows 0..255)
        #pragma unroll
        for (int it = 0; it < 8; ++it) {
            int o   = it * 4096 + tid * 16;
            int r   = o >> 7;
            int scb = (o & 127) ^ ((r & 7) << 4);
            GLOAD_LDS16((const char*)Bt + (size_t)r * 4608 + (size_t)kt * 2 + scb, Bb + o);
        }
        __syncthreads();   // compiler drains vmcnt before barrier
        #pragma unroll
        for (int kk = 0; kk < 2; ++kk) {
            const int koff = kk * 32 + (lane >> 4) * 8;
            bf16x8 af[4], bfr[4];
            #pragma unroll
            for (int i = 0; i < 4; ++i) {
                int ar = i * 16 + (lane & 15);
                af[i] = *(const bf16x8*)(Ab + ((ar * 128 + koff * 2) ^ ((ar & 7) << 4)));
            }
            #pragma unroll
            for (int j = 0; j < 4; ++j) {
                int br = wn + j * 16 + (lane & 15);
                bfr[j] = *(const bf16x8*)(Bb + ((br * 128 + koff * 2) ^ ((br & 7) << 4)));
            }
            #pragma unroll
            for (int i = 0; i < 4; ++i)
                #pragma unroll
                for (int j = 0; j < 4; ++j)
                    acc[i][j] = __builtin_amdgcn_mfma_f32_16x16x32_bf16(af[i], bfr[j], acc[i][j], 0, 0, 0);
        }
    }

    // D mapping: col=lane&15, row=(lane>>4)*4+reg
    const int col = lane & 15;
    const int r0  = (lane >> 4) * 4;
    #pragma unroll
    for (int i = 0; i < 4; ++i) {
        #pragma unroll
        for (int j = 0; j < 4; ++j) {
            int gn = wn + j * 16 + col;
            float bv = bias[gn];
            #pragma unroll
            for (int rr = 0; rr < 4; ++rr) {
                int gm = m0 + i * 16 + r0 + rr;
                if (gm < M) out[(size_t)gm * 256 + gn] = acc[i][j][rr] + bv;
            }
        }
    }
}

// ---------------------------------------------------------------- launch
extern "C" void kernel_launch(void* const* d_in, const int* in_sizes, int n_in,
                              void* d_out, int out_size, void* d_ws, size_t ws_size,
                              hipStream_t stream) {
    const int*   edge_index = (const int*)d_in[0];   // [2][E]
    const float* x          = (const float*)d_in[1]; // [M][256]
    const int*   edge_type  = (const int*)d_in[2];   // [E]
    const float* weight     = (const float*)d_in[3]; // [8][256][256]
    const float* h_bias     = (const float*)d_in[4]; // [256]
    const float* loop_w     = (const float*)d_in[5]; // [256][256]
    float* out = (float*)d_out;

    const int M = in_sizes[1] / 256;   // 50000
    const int E = in_sizes[2];         // 800000

    // workspace: Zcat 230.4MB | wbT 1.18MB | cnt | off | bsum | bsumo | recs
    char* ws = (char*)d_ws;
    size_t off_b = 0;
    unsigned short* Zcat = (unsigned short*)(ws + off_b);
    off_b += (((size_t)M * 2304 * 2) + 255) & ~(size_t)255;
    unsigned short* wbT = (unsigned short*)(ws + off_b);
    off_b += (((size_t)256 * 2304 * 2) + 255) & ~(size_t)255;
    unsigned* cnt = (unsigned*)(ws + off_b);
    off_b += (((size_t)(M + 1) * 4) + 255) & ~(size_t)255;
    unsigned* off = (unsigned*)(ws + off_b);
    off_b += (((size_t)(M + 1) * 4) + 255) & ~(size_t)255;
    unsigned* bsum = (unsigned*)(ws + off_b);
    off_b += 256;
    unsigned* bsumo = (unsigned*)(ws + off_b);
    off_b += 256;
    unsigned* recs = (unsigned*)(ws + off_b);

    const int nb = (M + 1023) / 1024;   // 49 scan blocks (<= 64)

    // counting sort of edges by dst
    rgcn_zero<<<(M + 255) / 256, 256, 0, stream>>>(cnt, M);
    rgcn_hist<<<(E + 255) / 256, 256, 0, stream>>>(edge_index, cnt, E);
    rgcn_scan1<<<nb, 1024, 0, stream>>>(cnt, off, bsum, M);
    rgcn_scan2<<<1, 64, 0, stream>>>(bsum, bsumo, off, nb, M);
    rgcn_scan3<<<(M + 255) / 256, 256, 0, stream>>>(off, bsumo, cnt, M);
    rgcn_scatter<<<(E + 255) / 256, 256, 0, stream>>>(edge_index, edge_type, cnt, recs, E);

    // bf16 x into Zcat[:, 2048:2304]; weights transposed+scaled
    rgcn_cvt<<<(M + 3) / 4, 256, 0, stream>>>(x, Zcat, M);
    rgcn_wbt<<<dim3(9, 256), 256, 0, stream>>>(weight, loop_w, wbT);

    // per-dst register aggregation -> Zcat[:, 0:2048]
    rgcn_agg<<<(M + 3) / 4, 256, 0, stream>>>(recs, off, Zcat, M);

    // single fused GEMM -> out (BN=256 covers all of N, BM=64 for occupancy)
    rgcn_gemm<<<(M + BM - 1) / BM, 256, 0, stream>>>(Zcat, wbT, out, h_bias, M);
}

// Round 6
// 343.916 us; speedup vs baseline: 1.1357x; 1.0449x over previous
//
#include <hip/hip_runtime.h>

typedef __bf16 bf16x8 __attribute__((ext_vector_type(8)));
typedef float f32x4 __attribute__((ext_vector_type(4)));

static __device__ __forceinline__ unsigned short f2bf(float f) {
    unsigned u = __builtin_bit_cast(unsigned, f);
    u += 0x7FFFu + ((u >> 16) & 1u);
    return (unsigned short)(u >> 16);
}
static __device__ __forceinline__ float bf2f(unsigned short h) {
    return __builtin_bit_cast(float, ((unsigned)h) << 16);
}

// async 16B global->LDS (linear LDS dest: wave-uniform base + lane*16)
#define GLOAD_LDS16(g, l)                                              \
    __builtin_amdgcn_global_load_lds(                                  \
        (const __attribute__((address_space(1))) unsigned int*)(g),    \
        (__attribute__((address_space(3))) unsigned int*)(l), 16, 0, 0)

// ---------------------------------------------------------------- tiny utils
__global__ __launch_bounds__(256) void rgcn_zero(unsigned* __restrict__ p, int n) {
    int i = blockIdx.x * 256 + threadIdx.x;
    if (i < n) p[i] = 0;
}

// histogram of dst
__global__ __launch_bounds__(256) void rgcn_hist(const int* __restrict__ ei,
                                                 unsigned* __restrict__ cnt, int E) {
    int e = blockIdx.x * 256 + threadIdx.x;
    if (e < E) atomicAdd(&cnt[ei[E + e]], 1u);
}

// ---------------- hierarchical exclusive scan (3 kernels) ----------------
__global__ __launch_bounds__(1024) void rgcn_scan1(const unsigned* __restrict__ cnt,
                                                   unsigned* __restrict__ off,
                                                   unsigned* __restrict__ bsum, int n) {
    __shared__ unsigned ws[16];
    const int t = threadIdx.x, lane = t & 63, wv = t >> 6;
    int i = blockIdx.x * 1024 + t;
    unsigned v = (i < n) ? cnt[i] : 0;
    unsigned s = v;
    #pragma unroll
    for (int d = 1; d < 64; d <<= 1) {
        unsigned u = __shfl_up(s, d, 64);
        if (lane >= d) s += u;
    }
    if (lane == 63) ws[wv] = s;
    __syncthreads();
    if (wv == 0) {
        unsigned b = (lane < 16) ? ws[lane] : 0;
        unsigned sb = b;
        #pragma unroll
        for (int d = 1; d < 16; d <<= 1) {
            unsigned u = __shfl_up(sb, d, 64);
            if (lane >= d) sb += u;
        }
        if (lane < 16) ws[lane] = sb - b;          // exclusive wave prefix
        if (lane == 15) bsum[blockIdx.x] = sb;     // block total
    }
    __syncthreads();
    if (i < n) off[i] = ws[wv] + (s - v);
}

__global__ __launch_bounds__(64) void rgcn_scan2(unsigned* __restrict__ bsum,
                                                 unsigned* __restrict__ bsumo,
                                                 unsigned* __restrict__ off, int nb, int n) {
    const int lane = threadIdx.x & 63;
    unsigned b = (lane < nb) ? bsum[lane] : 0;
    unsigned s = b;
    #pragma unroll
    for (int d = 1; d < 64; d <<= 1) {
        unsigned u = __shfl_up(s, d, 64);
        if (lane >= d) s += u;
    }
    if (lane < nb) bsumo[lane] = s - b;
    if (lane == 63) off[n] = s;
}

__global__ __launch_bounds__(256) void rgcn_scan3(unsigned* __restrict__ off,
                                                  const unsigned* __restrict__ bsumo,
                                                  unsigned* __restrict__ cur, int n) {
    int i = blockIdx.x * 256 + threadIdx.x;
    if (i < n) {
        unsigned v = off[i] + bsumo[i >> 10];
        off[i] = v;
        cur[i] = v;
    }
}

// scatter packed records (src | rel<<16) into dst-sorted order
__global__ __launch_bounds__(256) void rgcn_scatter(const int* __restrict__ ei,
                                                    const int* __restrict__ et,
                                                    unsigned* __restrict__ cur,
                                                    unsigned* __restrict__ recs, int E) {
    int e = blockIdx.x * 256 + threadIdx.x;
    if (e < E) {
        int dst = ei[E + e];
        unsigned p = atomicAdd(&cur[dst], 1u);
        recs[p] = (unsigned)ei[e] | ((unsigned)et[e] << 16);
    }
}

// write bf16 x into Zcat columns 2048..2303 (one wave per node row)
__global__ __launch_bounds__(256) void rgcn_cvt(const float* __restrict__ x,
                                                unsigned short* __restrict__ Z, int M) {
    int w = (blockIdx.x * 256 + threadIdx.x) >> 6;
    int lane = threadIdx.x & 63;
    if (w >= M) return;
    float4 v = *(const float4*)(x + (size_t)w * 256 + lane * 4);
    ushort4 o;
    o.x = f2bf(v.x); o.y = f2bf(v.y); o.z = f2bf(v.z); o.w = f2bf(v.w);
    *(ushort4*)(Z + (size_t)w * 2304 + 2048 + lane * 4) = o;
}

// wbT[n][kc]: kc<2048 -> weight[kc>>8][kc&255][n]; else loop_w[kc-2048][n]; both * sqrt(0.5)
__global__ __launch_bounds__(256) void rgcn_wbt(const float* __restrict__ w,
                                                const float* __restrict__ lw,
                                                unsigned short* __restrict__ wbT) {
    int kc = blockIdx.x * 256 + threadIdx.x;   // 0..2303
    int n  = blockIdx.y;                       // 0..255
    if (kc >= 2304) return;
    float v;
    if (kc < 2048) {
        int r = kc >> 8, k = kc & 255;
        v = w[((size_t)r * 256 + k) * 256 + n];
    } else {
        v = lw[(size_t)(kc - 2048) * 256 + n];
    }
    wbT[(size_t)n * 2304 + kc] = f2bf(v * 0.70710678118654752f);
}

// ---------------------------------------------------------------- aggregation
// grid-stride: each wave handles several dst nodes; per node sum bf16 x rows per
// relation into registers, write 8 Z rows. Stores of node n overlap loads of n+1.
__global__ __launch_bounds__(256) void rgcn_agg(const unsigned* __restrict__ recs,
                                                const unsigned* __restrict__ off,
                                                unsigned short* __restrict__ Z, int M) {
    const int gw0  = (blockIdx.x * 256 + threadIdx.x) >> 6;
    const int nw   = (gridDim.x * 256) >> 6;
    const int lane = threadIdx.x & 63;

#define LOADF(rec, fv)                                                                 \
    {                                                                                  \
        const ushort4 v_ = *(const ushort4*)(Z + (size_t)((rec) & 0xFFFFu) * 2304 +    \
                                             2048 + lane * 4);                         \
        fv[0] = bf2f(v_.x); fv[1] = bf2f(v_.y); fv[2] = bf2f(v_.z); fv[3] = bf2f(v_.w);\
    }
#define ACCUM(rec, fv)                                                                 \
    switch ((rec) >> 16) {                                                             \
        case 0: a0 += fv; break; case 1: a1 += fv; break;                              \
        case 2: a2 += fv; break; case 3: a3 += fv; break;                              \
        case 4: a4 += fv; break; case 5: a5 += fv; break;                              \
        case 6: a6 += fv; break; default: a7 += fv; break;                             \
    }

    for (int w = gw0; w < M; w += nw) {
        unsigned o0 = off[w], o1 = off[w + 1];
        f32x4 a0 = {}, a1 = {}, a2 = {}, a3 = {}, a4 = {}, a5 = {}, a6 = {}, a7 = {};

        unsigned i = o0;
        for (; i + 8 <= o1; i += 8) {   // 8-wide gather ILP
            unsigned r0 = recs[i],     r1 = recs[i + 1], r2 = recs[i + 2], r3 = recs[i + 3];
            unsigned r4 = recs[i + 4], r5 = recs[i + 5], r6 = recs[i + 6], r7 = recs[i + 7];
            f32x4 f0, f1, f2, f3, f4, f5, f6, f7;
            LOADF(r0, f0); LOADF(r1, f1); LOADF(r2, f2); LOADF(r3, f3);
            LOADF(r4, f4); LOADF(r5, f5); LOADF(r6, f6); LOADF(r7, f7);
            ACCUM(r0, f0); ACCUM(r1, f1); ACCUM(r2, f2); ACCUM(r3, f3);
            ACCUM(r4, f4); ACCUM(r5, f5); ACCUM(r6, f6); ACCUM(r7, f7);
        }
        for (; i < o1; ++i) {
            unsigned r0 = recs[i];
            f32x4 f0;
            LOADF(r0, f0);
            ACCUM(r0, f0);
        }

        unsigned short* zr = Z + (size_t)w * 2304 + lane * 4;
#define ST(rr, ax)                                                                     \
        {                                                                              \
            ushort4 o_;                                                                \
            o_.x = f2bf(ax[0]); o_.y = f2bf(ax[1]);                                    \
            o_.z = f2bf(ax[2]); o_.w = f2bf(ax[3]);                                    \
            *(ushort4*)(zr + rr * 256) = o_;                                           \
        }
        ST(0, a0) ST(1, a1) ST(2, a2) ST(3, a3) ST(4, a4) ST(5, a5) ST(6, a6) ST(7, a7)
#undef ST
    }
#undef LOADF
#undef ACCUM
}

// ---------------------------------------------------------------- GEMM
// out[M x 256] = Zcat[M x 2304] @ wbT^T + bias
// 64x256 tile, counted-vmcnt pipeline (T3-minimum):
//   compute(t) -> raw barrier -> issue B(t+1)(L2) + A(t+2)(HBM) -> vmcnt(2) -> raw barrier
// A double-buffered (2-chunk HBM headroom), B single-buffered. LDS 48KB -> 3 blocks/CU.
#define BM 64
#define BK 64
#define NCH 36   // 2304 / 64

__global__ __launch_bounds__(256) void rgcn_gemm(
    const unsigned short* __restrict__ A,    // Zcat [M][2304]
    const unsigned short* __restrict__ Bt,   // wbT  [256][2304]
    float* __restrict__ out,                 // [M][256]
    const float* __restrict__ bias,          // [256]
    int M)
{
    __shared__ char lds[8192 * 2 + 32768];   // A dbuf 2x8KB + B 32KB
    char* Ab0 = lds;
    char* Ab1 = lds + 8192;
    char* Bb  = lds + 16384;

    const int tid  = threadIdx.x;
    const int lane = tid & 63;
    const int wid  = tid >> 6;
    const int wn   = wid * 64;           // wave column offset (0/64/128/192)
    const int m0   = blockIdx.x * BM;

    f32x4 acc[4][4] = {};

    auto stageA = [&](int chunk, char* dst) {
        #pragma unroll
        for (int it = 0; it < 2; ++it) {
            int o   = it * 4096 + tid * 16;
            int r   = o >> 7;                       // row 0..63
            int scb = (o & 127) ^ ((r & 7) << 4);   // pre-swizzled source col byte
            int ga  = m0 + r; if (ga >= M) ga = M - 1;
            GLOAD_LDS16((const char*)A + (size_t)ga * 4608 + (size_t)chunk * 128 + scb, dst + o);
        }
    };
    auto stageB = [&](int chunk) {
        #pragma unroll
        for (int it = 0; it < 8; ++it) {
            int o   = it * 4096 + tid * 16;
            int r   = o >> 7;                       // row 0..255
            int scb = (o & 127) ^ ((r & 7) << 4);
            GLOAD_LDS16((const char*)Bt + (size_t)r * 4608 + (size_t)chunk * 128 + scb, Bb + o);
        }
    };

    // prologue: A(0), B(0), A(1) in flight; wait all but A(1)
    stageA(0, Ab0);
    stageB(0);
    stageA(1, Ab1);
    asm volatile("s_waitcnt vmcnt(2)" ::: "memory");
    __builtin_amdgcn_s_barrier();
    __builtin_amdgcn_sched_barrier(0);

    for (int t = 0; t < NCH; ++t) {
        const char* Acur = (t & 1) ? Ab1 : Ab0;
        #pragma unroll
        for (int kk = 0; kk < 2; ++kk) {
            const int koff = kk * 32 + (lane >> 4) * 8;
            bf16x8 af[4], bfr[4];
            #pragma unroll
            for (int i = 0; i < 4; ++i) {
                int ar = i * 16 + (lane & 15);
                af[i] = *(const bf16x8*)(Acur + ((ar * 128 + koff * 2) ^ ((ar & 7) << 4)));
            }
            #pragma unroll
            for (int j = 0; j < 4; ++j) {
                int br = wn + j * 16 + (lane & 15);
                bfr[j] = *(const bf16x8*)(Bb + ((br * 128 + koff * 2) ^ ((br & 7) << 4)));
            }
            #pragma unroll
            for (int i = 0; i < 4; ++i)
                #pragma unroll
                for (int j = 0; j < 4; ++j)
                    acc[i][j] = __builtin_amdgcn_mfma_f32_16x16x32_bf16(af[i], bfr[j], acc[i][j], 0, 0, 0);
        }

        if (t < NCH - 1) {
            // all ds_read results consumed by MFMAs (lgkm drained); raw barrier only
            __builtin_amdgcn_s_barrier();
            __builtin_amdgcn_sched_barrier(0);
            stageB(t + 1);                                   // 8 loads, L2-resident
            int tA = (t + 2 < NCH) ? t + 2 : NCH - 1;        // clamp (data unused past end)
            stageA(tA, (t & 1) ? Ab1 : Ab0);                 // 2 loads, HBM, 2-chunk headroom
            asm volatile("s_waitcnt vmcnt(2)" ::: "memory"); // B(t+1)+A(t+1) done; A(t+2) flying
            __builtin_amdgcn_s_barrier();
            __builtin_amdgcn_sched_barrier(0);
        }
    }

    // D mapping: col=lane&15, row=(lane>>4)*4+reg
    const int col = lane & 15;
    const int r0  = (lane >> 4) * 4;
    #pragma unroll
    for (int i = 0; i < 4; ++i) {
        #pragma unroll
        for (int j = 0; j < 4; ++j) {
            int gn = wn + j * 16 + col;
            float bv = bias[gn];
            #pragma unroll
            for (int rr = 0; rr < 4; ++rr) {
                int gm = m0 + i * 16 + r0 + rr;
                if (gm < M) out[(size_t)gm * 256 + gn] = acc[i][j][rr] + bv;
            }
        }
    }
}

// ---------------------------------------------------------------- launch
extern "C" void kernel_launch(void* const* d_in, const int* in_sizes, int n_in,
                              void* d_out, int out_size, void* d_ws, size_t ws_size,
                              hipStream_t stream) {
    const int*   edge_index = (const int*)d_in[0];   // [2][E]
    const float* x          = (const float*)d_in[1]; // [M][256]
    const int*   edge_type  = (const int*)d_in[2];   // [E]
    const float* weight     = (const float*)d_in[3]; // [8][256][256]
    const float* h_bias     = (const float*)d_in[4]; // [256]
    const float* loop_w     = (const float*)d_in[5]; // [256][256]
    float* out = (float*)d_out;

    const int M = in_sizes[1] / 256;   // 50000
    const int E = in_sizes[2];         // 800000

    // workspace: Zcat 230.4MB | wbT 1.18MB | cnt | off | bsum | bsumo | recs
    char* ws = (char*)d_ws;
    size_t off_b = 0;
    unsigned short* Zcat = (unsigned short*)(ws + off_b);
    off_b += (((size_t)M * 2304 * 2) + 255) & ~(size_t)255;
    unsigned short* wbT = (unsigned short*)(ws + off_b);
    off_b += (((size_t)256 * 2304 * 2) + 255) & ~(size_t)255;
    unsigned* cnt = (unsigned*)(ws + off_b);
    off_b += (((size_t)(M + 1) * 4) + 255) & ~(size_t)255;
    unsigned* off = (unsigned*)(ws + off_b);
    off_b += (((size_t)(M + 1) * 4) + 255) & ~(size_t)255;
    unsigned* bsum = (unsigned*)(ws + off_b);
    off_b += 256;
    unsigned* bsumo = (unsigned*)(ws + off_b);
    off_b += 256;
    unsigned* recs = (unsigned*)(ws + off_b);

    const int nb = (M + 1023) / 1024;   // 49 scan blocks (<= 64)

    // counting sort of edges by dst
    rgcn_zero<<<(M + 255) / 256, 256, 0, stream>>>(cnt, M);
    rgcn_hist<<<(E + 255) / 256, 256, 0, stream>>>(edge_index, cnt, E);
    rgcn_scan1<<<nb, 1024, 0, stream>>>(cnt, off, bsum, M);
    rgcn_scan2<<<1, 64, 0, stream>>>(bsum, bsumo, off, nb, M);
    rgcn_scan3<<<(M + 255) / 256, 256, 0, stream>>>(off, bsumo, cnt, M);
    rgcn_scatter<<<(E + 255) / 256, 256, 0, stream>>>(edge_index, edge_type, cnt, recs, E);

    // bf16 x into Zcat[:, 2048:2304]; weights transposed+scaled
    rgcn_cvt<<<(M + 3) / 4, 256, 0, stream>>>(x, Zcat, M);
    rgcn_wbt<<<dim3(9, 256), 256, 0, stream>>>(weight, loop_w, wbT);

    // per-dst register aggregation -> Zcat[:, 0:2048] (grid-stride, resident blocks)
    rgcn_agg<<<2560, 256, 0, stream>>>(recs, off, Zcat, M);

    // single fused GEMM -> out (BN=256 covers all of N, BM=64, pipelined)
    rgcn_gemm<<<(M + BM - 1) / BM, 256, 0, stream>>>(Zcat, wbT, out, h_bias, M);
}

// Round 7
// 333.054 us; speedup vs baseline: 1.1727x; 1.0326x over previous
//
#include <hip/hip_runtime.h>

typedef __bf16 bf16x8 __attribute__((ext_vector_type(8)));
typedef float f32x4 __attribute__((ext_vector_type(4)));

static __device__ __forceinline__ unsigned short f2bf(float f) {
    unsigned u = __builtin_bit_cast(unsigned, f);
    u += 0x7FFFu + ((u >> 16) & 1u);
    return (unsigned short)(u >> 16);
}
static __device__ __forceinline__ float bf2f(unsigned short h) {
    return __builtin_bit_cast(float, ((unsigned)h) << 16);
}

// async 16B global->LDS (linear LDS dest: wave-uniform base + lane*16)
#define GLOAD_LDS16(g, l)                                              \
    __builtin_amdgcn_global_load_lds(                                  \
        (const __attribute__((address_space(1))) unsigned int*)(g),    \
        (__attribute__((address_space(3))) unsigned int*)(l), 16, 0, 0)

// ---------------------------------------------------------------- tiny utils
__global__ __launch_bounds__(256) void rgcn_zero(unsigned* __restrict__ p, int n) {
    int i = blockIdx.x * 256 + threadIdx.x;
    if (i < n) p[i] = 0;
}

// fused prep: blocks [0,HB) hist | [HB, HB+CB) cvt | [HB+CB, HB+CB+WB) wbt
// HB = ceil(E/256), CB = ceil(M/4), WB = 2304
__global__ __launch_bounds__(256) void rgcn_prep(const int* __restrict__ ei,
                                                 unsigned* __restrict__ cnt,
                                                 const float* __restrict__ x,
                                                 unsigned short* __restrict__ Z,
                                                 const float* __restrict__ w,
                                                 const float* __restrict__ lw,
                                                 unsigned short* __restrict__ wbT,
                                                 int E, int M, int HB, int CB) {
    const int b = blockIdx.x;
    const int t = threadIdx.x;
    if (b < HB) {                     // ---- histogram of dst
        int e = b * 256 + t;
        if (e < E) atomicAdd(&cnt[ei[E + e]], 1u);
    } else if (b < HB + CB) {         // ---- bf16 x -> Zcat[:, 2048:2304]
        int wv = ((b - HB) * 256 + t) >> 6;
        int lane = t & 63;
        if (wv < M) {
            float4 v = *(const float4*)(x + (size_t)wv * 256 + lane * 4);
            ushort4 o;
            o.x = f2bf(v.x); o.y = f2bf(v.y); o.z = f2bf(v.z); o.w = f2bf(v.w);
            *(ushort4*)(Z + (size_t)wv * 2304 + 2048 + lane * 4) = o;
        }
    } else {                          // ---- wbT build (2304 blocks)
        int bb = b - HB - CB;         // 0..2303
        int kc = (bb % 9) * 256 + t;  // 0..2303
        int n  = bb / 9;              // 0..255
        if (kc < 2304) {
            float v;
            if (kc < 2048) {
                int r = kc >> 8, k = kc & 255;
                v = w[((size_t)r * 256 + k) * 256 + n];
            } else {
                v = lw[(size_t)(kc - 2048) * 256 + n];
            }
            wbT[(size_t)n * 2304 + kc] = f2bf(v * 0.70710678118654752f);
        }
    }
}

// ---------------- hierarchical exclusive scan (3 kernels) ----------------
__global__ __launch_bounds__(1024) void rgcn_scan1(const unsigned* __restrict__ cnt,
                                                   unsigned* __restrict__ off,
                                                   unsigned* __restrict__ bsum, int n) {
    __shared__ unsigned ws[16];
    const int t = threadIdx.x, lane = t & 63, wv = t >> 6;
    int i = blockIdx.x * 1024 + t;
    unsigned v = (i < n) ? cnt[i] : 0;
    unsigned s = v;
    #pragma unroll
    for (int d = 1; d < 64; d <<= 1) {
        unsigned u = __shfl_up(s, d, 64);
        if (lane >= d) s += u;
    }
    if (lane == 63) ws[wv] = s;
    __syncthreads();
    if (wv == 0) {
        unsigned b = (lane < 16) ? ws[lane] : 0;
        unsigned sb = b;
        #pragma unroll
        for (int d = 1; d < 16; d <<= 1) {
            unsigned u = __shfl_up(sb, d, 64);
            if (lane >= d) sb += u;
        }
        if (lane < 16) ws[lane] = sb - b;          // exclusive wave prefix
        if (lane == 15) bsum[blockIdx.x] = sb;     // block total
    }
    __syncthreads();
    if (i < n) off[i] = ws[wv] + (s - v);
}

__global__ __launch_bounds__(64) void rgcn_scan2(unsigned* __restrict__ bsum,
                                                 unsigned* __restrict__ bsumo,
                                                 unsigned* __restrict__ off, int nb, int n) {
    const int lane = threadIdx.x & 63;
    unsigned b = (lane < nb) ? bsum[lane] : 0;
    unsigned s = b;
    #pragma unroll
    for (int d = 1; d < 64; d <<= 1) {
        unsigned u = __shfl_up(s, d, 64);
        if (lane >= d) s += u;
    }
    if (lane < nb) bsumo[lane] = s - b;
    if (lane == 63) off[n] = s;
}

__global__ __launch_bounds__(256) void rgcn_scan3(unsigned* __restrict__ off,
                                                  const unsigned* __restrict__ bsumo,
                                                  unsigned* __restrict__ cur, int n) {
    int i = blockIdx.x * 256 + threadIdx.x;
    if (i < n) {
        unsigned v = off[i] + bsumo[i >> 10];
        off[i] = v;
        cur[i] = v;
    }
}

// scatter packed records (src | rel<<16) into dst-sorted order
__global__ __launch_bounds__(256) void rgcn_scatter(const int* __restrict__ ei,
                                                    const int* __restrict__ et,
                                                    unsigned* __restrict__ cur,
                                                    unsigned* __restrict__ recs, int E) {
    int e = blockIdx.x * 256 + threadIdx.x;
    if (e < E) {
        int dst = ei[E + e];
        unsigned p = atomicAdd(&cur[dst], 1u);
        recs[p] = (unsigned)ei[e] | ((unsigned)et[e] << 16);
    }
}

// ---------------------------------------------------------------- aggregation
// one wave per dst node (grid-stride). Lane l loads recs[o0+l] (ONE vector load
// per 64 edges); per-edge records via __shfl (register-only). Gathers issued in
// 16-deep batches -> 2x MLP vs round 6, no rec-load on the critical path.
__global__ __launch_bounds__(256) void rgcn_agg(const unsigned* __restrict__ recs,
                                                const unsigned* __restrict__ off,
                                                unsigned short* __restrict__ Z, int M) {
    const int gw0  = (blockIdx.x * 256 + threadIdx.x) >> 6;
    const int nw   = (gridDim.x * 256) >> 6;
    const int lane = threadIdx.x & 63;
    const unsigned short* Zx = Z + 2048 + lane * 4;   // gather base (x cols)

#define GATHER(rr) (*(const ushort4*)(Zx + (size_t)((rr) & 0xFFFFu) * 2304))
#define ACCUM(rec, v_)                                                                 \
    {                                                                                  \
        f32x4 fv;                                                                      \
        fv[0] = bf2f(v_.x); fv[1] = bf2f(v_.y); fv[2] = bf2f(v_.z); fv[3] = bf2f(v_.w);\
        switch ((rec) >> 16) {                                                         \
            case 0: a0 += fv; break; case 1: a1 += fv; break;                          \
            case 2: a2 += fv; break; case 3: a3 += fv; break;                          \
            case 4: a4 += fv; break; case 5: a5 += fv; break;                          \
            case 6: a6 += fv; break; default: a7 += fv; break;                         \
        }                                                                              \
    }

    for (int w = gw0; w < M; w += nw) {
        const unsigned o0 = off[w], o1 = off[w + 1];
        f32x4 a0 = {}, a1 = {}, a2 = {}, a3 = {}, a4 = {}, a5 = {}, a6 = {}, a7 = {};

        for (unsigned base = o0; base < o1; base += 64) {
            const unsigned wdeg = (o1 - base < 64u) ? (o1 - base) : 64u;
            const unsigned myrec = ((unsigned)lane < wdeg) ? recs[base + lane] : 0u;

            unsigned j = 0;
            for (; j + 16 <= wdeg; j += 16) {
                unsigned rr[16];
                #pragma unroll
                for (int u = 0; u < 16; ++u) rr[u] = __shfl(myrec, (int)(j + u), 64);
                ushort4 vv[16];
                #pragma unroll
                for (int u = 0; u < 16; ++u) vv[u] = GATHER(rr[u]);
                #pragma unroll
                for (int u = 0; u < 16; ++u) ACCUM(rr[u], vv[u]);
            }
            for (; j + 4 <= wdeg; j += 4) {
                unsigned rr[4];
                #pragma unroll
                for (int u = 0; u < 4; ++u) rr[u] = __shfl(myrec, (int)(j + u), 64);
                ushort4 vv[4];
                #pragma unroll
                for (int u = 0; u < 4; ++u) vv[u] = GATHER(rr[u]);
                #pragma unroll
                for (int u = 0; u < 4; ++u) ACCUM(rr[u], vv[u]);
            }
            for (; j < wdeg; ++j) {
                unsigned r_ = __shfl(myrec, (int)j, 64);
                ushort4 v_ = GATHER(r_);
                ACCUM(r_, v_);
            }
        }

        unsigned short* zr = Z + (size_t)w * 2304 + lane * 4;
#define ST(rr_, ax)                                                                    \
        {                                                                              \
            ushort4 o_;                                                                \
            o_.x = f2bf(ax[0]); o_.y = f2bf(ax[1]);                                    \
            o_.z = f2bf(ax[2]); o_.w = f2bf(ax[3]);                                    \
            *(ushort4*)(zr + rr_ * 256) = o_;                                          \
        }
        ST(0, a0) ST(1, a1) ST(2, a2) ST(3, a3) ST(4, a4) ST(5, a5) ST(6, a6) ST(7, a7)
#undef ST
    }
#undef GATHER
#undef ACCUM
}

// ---------------------------------------------------------------- GEMM
// out[M x 256] = Zcat[M x 2304] @ wbT^T + bias
// 64x256 tile, counted-vmcnt pipeline:
//   compute(t) -> raw barrier -> issue B(t+1)(L2) + A(t+2)(HBM) -> vmcnt(2) -> raw barrier
#define BM 64
#define BK 64
#define NCH 36   // 2304 / 64

__global__ __launch_bounds__(256) void rgcn_gemm(
    const unsigned short* __restrict__ A,    // Zcat [M][2304]
    const unsigned short* __restrict__ Bt,   // wbT  [256][2304]
    float* __restrict__ out,                 // [M][256]
    const float* __restrict__ bias,          // [256]
    int M)
{
    __shared__ char lds[8192 * 2 + 32768];   // A dbuf 2x8KB + B 32KB
    char* Ab0 = lds;
    char* Ab1 = lds + 8192;
    char* Bb  = lds + 16384;

    const int tid  = threadIdx.x;
    const int lane = tid & 63;
    const int wid  = tid >> 6;
    const int wn   = wid * 64;           // wave column offset (0/64/128/192)
    const int m0   = blockIdx.x * BM;

    f32x4 acc[4][4] = {};

    auto stageA = [&](int chunk, char* dst) {
        #pragma unroll
        for (int it = 0; it < 2; ++it) {
            int o   = it * 4096 + tid * 16;
            int r   = o >> 7;                       // row 0..63
            int scb = (o & 127) ^ ((r & 7) << 4);   // pre-swizzled source col byte
            int ga  = m0 + r; if (ga >= M) ga = M - 1;
            GLOAD_LDS16((const char*)A + (size_t)ga * 4608 + (size_t)chunk * 128 + scb, dst + o);
        }
    };
    auto stageB = [&](int chunk) {
        #pragma unroll
        for (int it = 0; it < 8; ++it) {
            int o   = it * 4096 + tid * 16;
            int r   = o >> 7;                       // row 0..255
            int scb = (o & 127) ^ ((r & 7) << 4);
            GLOAD_LDS16((const char*)Bt + (size_t)r * 4608 + (size_t)chunk * 128 + scb, Bb + o);
        }
    };

    // prologue: A(0), B(0), A(1) in flight; wait all but A(1)
    stageA(0, Ab0);
    stageB(0);
    stageA(1, Ab1);
    asm volatile("s_waitcnt vmcnt(2)" ::: "memory");
    __builtin_amdgcn_s_barrier();
    __builtin_amdgcn_sched_barrier(0);

    for (int t = 0; t < NCH; ++t) {
        const char* Acur = (t & 1) ? Ab1 : Ab0;
        #pragma unroll
        for (int kk = 0; kk < 2; ++kk) {
            const int koff = kk * 32 + (lane >> 4) * 8;
            bf16x8 af[4], bfr[4];
            #pragma unroll
            for (int i = 0; i < 4; ++i) {
                int ar = i * 16 + (lane & 15);
                af[i] = *(const bf16x8*)(Acur + ((ar * 128 + koff * 2) ^ ((ar & 7) << 4)));
            }
            #pragma unroll
            for (int j = 0; j < 4; ++j) {
                int br = wn + j * 16 + (lane & 15);
                bfr[j] = *(const bf16x8*)(Bb + ((br * 128 + koff * 2) ^ ((br & 7) << 4)));
            }
            #pragma unroll
            for (int i = 0; i < 4; ++i)
                #pragma unroll
                for (int j = 0; j < 4; ++j)
                    acc[i][j] = __builtin_amdgcn_mfma_f32_16x16x32_bf16(af[i], bfr[j], acc[i][j], 0, 0, 0);
        }

        if (t < NCH - 1) {
            __builtin_amdgcn_s_barrier();
            __builtin_amdgcn_sched_barrier(0);
            stageB(t + 1);                                   // 8 loads, L2-resident
            int tA = (t + 2 < NCH) ? t + 2 : NCH - 1;        // clamp (data unused past end)
            stageA(tA, (t & 1) ? Ab1 : Ab0);                 // 2 loads, HBM, 2-chunk headroom
            asm volatile("s_waitcnt vmcnt(2)" ::: "memory"); // B(t+1)+A(t+1) done; A(t+2) flying
            __builtin_amdgcn_s_barrier();
            __builtin_amdgcn_sched_barrier(0);
        }
    }

    // D mapping: col=lane&15, row=(lane>>4)*4+reg
    const int col = lane & 15;
    const int r0  = (lane >> 4) * 4;
    #pragma unroll
    for (int i = 0; i < 4; ++i) {
        #pragma unroll
        for (int j = 0; j < 4; ++j) {
            int gn = wn + j * 16 + col;
            float bv = bias[gn];
            #pragma unroll
            for (int rr = 0; rr < 4; ++rr) {
                int gm = m0 + i * 16 + r0 + rr;
                if (gm < M) out[(size_t)gm * 256 + gn] = acc[i][j][rr] + bv;
            }
        }
    }
}

// ---------------------------------------------------------------- launch
extern "C" void kernel_launch(void* const* d_in, const int* in_sizes, int n_in,
                              void* d_out, int out_size, void* d_ws, size_t ws_size,
                              hipStream_t stream) {
    const int*   edge_index = (const int*)d_in[0];   // [2][E]
    const float* x          = (const float*)d_in[1]; // [M][256]
    const int*   edge_type  = (const int*)d_in[2];   // [E]
    const float* weight     = (const float*)d_in[3]; // [8][256][256]
    const float* h_bias     = (const float*)d_in[4]; // [256]
    const float* loop_w     = (const float*)d_in[5]; // [256][256]
    float* out = (float*)d_out;

    const int M = in_sizes[1] / 256;   // 50000
    const int E = in_sizes[2];         // 800000

    // workspace: Zcat 230.4MB | wbT 1.18MB | cnt | off | bsum | bsumo | recs
    char* ws = (char*)d_ws;
    size_t off_b = 0;
    unsigned short* Zcat = (unsigned short*)(ws + off_b);
    off_b += (((size_t)M * 2304 * 2) + 255) & ~(size_t)255;
    unsigned short* wbT = (unsigned short*)(ws + off_b);
    off_b += (((size_t)256 * 2304 * 2) + 255) & ~(size_t)255;
    unsigned* cnt = (unsigned*)(ws + off_b);
    off_b += (((size_t)(M + 1) * 4) + 255) & ~(size_t)255;
    unsigned* off = (unsigned*)(ws + off_b);
    off_b += (((size_t)(M + 1) * 4) + 255) & ~(size_t)255;
    unsigned* bsum = (unsigned*)(ws + off_b);
    off_b += 256;
    unsigned* bsumo = (unsigned*)(ws + off_b);
    off_b += 256;
    unsigned* recs = (unsigned*)(ws + off_b);

    const int nb = (M + 1023) / 1024;   // 49 scan blocks (<= 64)
    const int HB = (E + 255) / 256;     // 3125
    const int CB = (M + 3) / 4;         // 12500

    rgcn_zero<<<(M + 255) / 256, 256, 0, stream>>>(cnt, M);
    // fused: histogram + bf16-x + weight transpose (independent work)
    rgcn_prep<<<HB + CB + 2304, 256, 0, stream>>>(edge_index, cnt, x, Zcat,
                                                  weight, loop_w, wbT, E, M, HB, CB);
    rgcn_scan1<<<nb, 1024, 0, stream>>>(cnt, off, bsum, M);
    rgcn_scan2<<<1, 64, 0, stream>>>(bsum, bsumo, off, nb, M);
    rgcn_scan3<<<(M + 255) / 256, 256, 0, stream>>>(off, bsumo, cnt, M);
    rgcn_scatter<<<(E + 255) / 256, 256, 0, stream>>>(edge_index, edge_type, cnt, recs, E);

    // per-dst register aggregation -> Zcat[:, 0:2048]
    rgcn_agg<<<2560, 256, 0, stream>>>(recs, off, Zcat, M);

    // single fused GEMM -> out (BN=256 covers all of N, BM=64, pipelined)
    rgcn_gemm<<<(M + BM - 1) / BM, 256, 0, stream>>>(Zcat, wbT, out, h_bias, M);
}

// Round 9
// 311.459 us; speedup vs baseline: 1.2540x; 1.0693x over previous
//
#include <hip/hip_runtime.h>

typedef __bf16 bf16x8 __attribute__((ext_vector_type(8)));
typedef float f32x4 __attribute__((ext_vector_type(4)));

static __device__ __forceinline__ unsigned short f2bf(float f) {
    unsigned u = __builtin_bit_cast(unsigned, f);
    u += 0x7FFFu + ((u >> 16) & 1u);
    return (unsigned short)(u >> 16);
}
static __device__ __forceinline__ float bf2f(unsigned short h) {
    return __builtin_bit_cast(float, ((unsigned)h) << 16);
}

// async 16B global->LDS (linear LDS dest: wave-uniform base + lane*16)
#define GLOAD_LDS16(g, l)                                              \
    __builtin_amdgcn_global_load_lds(                                  \
        (const __attribute__((address_space(1))) unsigned int*)(g),    \
        (__attribute__((address_space(3))) unsigned int*)(l), 16, 0, 0)

// ---------------------------------------------------------------- fused prep
// blocks [0,HB) hist | [HB, HB+CB) cvt | [HB+CB, HB+CB+2304) wbt
__global__ __launch_bounds__(256) void rgcn_prep(const int* __restrict__ ei,
                                                 unsigned* __restrict__ cnt,
                                                 const float* __restrict__ x,
                                                 unsigned short* __restrict__ Z,
                                                 const float* __restrict__ w,
                                                 const float* __restrict__ lw,
                                                 unsigned short* __restrict__ wbT,
                                                 int E, int M, int HB, int CB) {
    const int b = blockIdx.x;
    const int t = threadIdx.x;
    if (b < HB) {                     // ---- histogram of dst
        int e = b * 256 + t;
        if (e < E) atomicAdd(&cnt[ei[E + e]], 1u);
    } else if (b < HB + CB) {         // ---- bf16 x -> Zcat[:, 2048:2304]
        int wv = ((b - HB) * 256 + t) >> 6;
        int lane = t & 63;
        if (wv < M) {
            float4 v = *(const float4*)(x + (size_t)wv * 256 + lane * 4);
            ushort4 o;
            o.x = f2bf(v.x); o.y = f2bf(v.y); o.z = f2bf(v.z); o.w = f2bf(v.w);
            *(ushort4*)(Z + (size_t)wv * 2304 + 2048 + lane * 4) = o;
        }
    } else {                          // ---- wbT build (2304 blocks)
        int bb = b - HB - CB;         // 0..2303
        int kc = (bb % 9) * 256 + t;  // 0..2303
        int n  = bb / 9;              // 0..255
        if (kc < 2304) {
            float v;
            if (kc < 2048) {
                int r = kc >> 8, k = kc & 255;
                v = w[((size_t)r * 256 + k) * 256 + n];
            } else {
                v = lw[(size_t)(kc - 2048) * 256 + n];
            }
            wbT[(size_t)n * 2304 + kc] = f2bf(v * 0.70710678118654752f);
        }
    }
}

// ---------------------------------------------------------------- single-kernel scan
// 49 blocks, all co-resident (grid << 256 CUs). Per-block local scan; block totals
// posted via device-scope atomics + spin on a zeroed counter; coherent readback
// via atomicAdd(p,0). Writes off[] and cur[] (cursor copy) and off[n]=E.
__global__ __launch_bounds__(1024) void rgcn_scan_all(const unsigned* __restrict__ cnt,
                                                      unsigned* __restrict__ off,
                                                      unsigned* __restrict__ cur,
                                                      unsigned* __restrict__ done,
                                                      unsigned* __restrict__ bsum,
                                                      int n, int nb) {
    __shared__ unsigned wsum[16];
    __shared__ unsigned bpre_s;
    const int t = threadIdx.x, lane = t & 63, wv = t >> 6;
    const int b = blockIdx.x;
    int i = b * 1024 + t;
    unsigned v = (i < n) ? cnt[i] : 0;
    unsigned s = v;
    #pragma unroll
    for (int d = 1; d < 64; d <<= 1) {
        unsigned u = __shfl_up(s, d, 64);
        if (lane >= d) s += u;
    }
    if (lane == 63) wsum[wv] = s;
    __syncthreads();
    if (wv == 0) {
        unsigned bb = (lane < 16) ? wsum[lane] : 0;
        unsigned sb = bb;
        #pragma unroll
        for (int d = 1; d < 16; d <<= 1) {
            unsigned u = __shfl_up(sb, d, 64);
            if (lane >= d) sb += u;
        }
        if (lane < 16) wsum[lane] = sb - bb;       // exclusive wave prefix
        if (lane == 15) {                          // post block total (release)
            atomicExch(&bsum[b], sb);
            __threadfence();
            atomicAdd(done, 1u);
        }
    }
    __syncthreads();
    if (t == 0) {                                  // spin until all blocks posted
        while (atomicAdd(done, 0u) < (unsigned)nb) __builtin_amdgcn_s_sleep(8);
    }
    __syncthreads();
    if (wv == 0) {                                 // cross-block exclusive prefix
        unsigned bv = (lane < nb) ? atomicAdd(&bsum[lane], 0u) : 0;
        unsigned sp = bv;
        #pragma unroll
        for (int d = 1; d < 64; d <<= 1) {
            unsigned u = __shfl_up(sp, d, 64);
            if (lane >= d) sp += u;
        }
        if (lane == b) bpre_s = sp - bv;
        if (b == 0 && lane == nb - 1) off[n] = sp; // grand total = E
    }
    __syncthreads();
    unsigned base = bpre_s + wsum[wv];
    if (i < n) {
        unsigned o = base + (s - v);
        off[i] = o;
        cur[i] = o;
    }
}

// scatter packed records (src | rel<<16) into dst-sorted order
__global__ __launch_bounds__(256) void rgcn_scatter(const int* __restrict__ ei,
                                                    const int* __restrict__ et,
                                                    unsigned* __restrict__ cur,
                                                    unsigned* __restrict__ recs, int E) {
    int e = blockIdx.x * 256 + threadIdx.x;
    if (e < E) {
        int dst = ei[E + e];
        unsigned p = atomicAdd(&cur[dst], 1u);
        recs[p] = (unsigned)ei[e] | ((unsigned)et[e] << 16);
    }
}

// ---------------------------------------------------------------- aggregation
// one wave per dst node (grid-stride). Lane l loads recs[o0+l]; per-edge records
// via __shfl; gathers in 16-deep batches. (Throughput-pinned at ~3.1 TB/s.)
__global__ __launch_bounds__(256) void rgcn_agg(const unsigned* __restrict__ recs,
                                                const unsigned* __restrict__ off,
                                                unsigned short* __restrict__ Z, int M) {
    const int gw0  = (blockIdx.x * 256 + threadIdx.x) >> 6;
    const int nw   = (gridDim.x * 256) >> 6;
    const int lane = threadIdx.x & 63;
    const unsigned short* Zx = Z + 2048 + lane * 4;   // gather base (x cols)

#define GATHER(rr) (*(const ushort4*)(Zx + (size_t)((rr) & 0xFFFFu) * 2304))
#define ACCUM(rec, v_)                                                                 \
    {                                                                                  \
        f32x4 fv;                                                                      \
        fv[0] = bf2f(v_.x); fv[1] = bf2f(v_.y); fv[2] = bf2f(v_.z); fv[3] = bf2f(v_.w);\
        switch ((rec) >> 16) {                                                         \
            case 0: a0 += fv; break; case 1: a1 += fv; break;                          \
            case 2: a2 += fv; break; case 3: a3 += fv; break;                          \
            case 4: a4 += fv; break; case 5: a5 += fv; break;                          \
            case 6: a6 += fv; break; default: a7 += fv; break;                         \
        }                                                                              \
    }

    for (int w = gw0; w < M; w += nw) {
        const unsigned o0 = off[w], o1 = off[w + 1];
        f32x4 a0 = {}, a1 = {}, a2 = {}, a3 = {}, a4 = {}, a5 = {}, a6 = {}, a7 = {};

        for (unsigned base = o0; base < o1; base += 64) {
            const unsigned wdeg = (o1 - base < 64u) ? (o1 - base) : 64u;
            const unsigned myrec = ((unsigned)lane < wdeg) ? recs[base + lane] : 0u;

            unsigned j = 0;
            for (; j + 16 <= wdeg; j += 16) {
                unsigned rr[16];
                #pragma unroll
                for (int u = 0; u < 16; ++u) rr[u] = __shfl(myrec, (int)(j + u), 64);
                ushort4 vv[16];
                #pragma unroll
                for (int u = 0; u < 16; ++u) vv[u] = GATHER(rr[u]);
                #pragma unroll
                for (int u = 0; u < 16; ++u) ACCUM(rr[u], vv[u]);
            }
            for (; j + 4 <= wdeg; j += 4) {
                unsigned rr[4];
                #pragma unroll
                for (int u = 0; u < 4; ++u) rr[u] = __shfl(myrec, (int)(j + u), 64);
                ushort4 vv[4];
                #pragma unroll
                for (int u = 0; u < 4; ++u) vv[u] = GATHER(rr[u]);
                #pragma unroll
                for (int u = 0; u < 4; ++u) ACCUM(rr[u], vv[u]);
            }
            for (; j < wdeg; ++j) {
                unsigned r_ = __shfl(myrec, (int)j, 64);
                ushort4 v_ = GATHER(r_);
                ACCUM(r_, v_);
            }
        }

        unsigned short* zr = Z + (size_t)w * 2304 + lane * 4;
#define ST(rr_, ax)                                                                    \
        {                                                                              \
            ushort4 o_;                                                                \
            o_.x = f2bf(ax[0]); o_.y = f2bf(ax[1]);                                    \
            o_.z = f2bf(ax[2]); o_.w = f2bf(ax[3]);                                    \
            *(ushort4*)(zr + rr_ * 256) = o_;                                          \
        }
        ST(0, a0) ST(1, a1) ST(2, a2) ST(3, a3) ST(4, a4) ST(5, a5) ST(6, a6) ST(7, a7)
#undef ST
    }
#undef GATHER
#undef ACCUM
}

// ---------------------------------------------------------------- GEMM v3
// out[M x 256] = Zcat[M x 2304] @ wbT^T + bias
// 256x256 tile, 8 waves, wave-tile 64x128 (4m x 2n) -> reads/MFMA 0.1875.
// A+B double-buffered (128KB LDS, 1 block/CU), counted vmcnt(8) pipeline.
#define BM 256
#define BK 64
#define NCH 36   // 2304 / 64

__global__ __launch_bounds__(512) void rgcn_gemm(
    const unsigned short* __restrict__ A,    // Zcat [M][2304]
    const unsigned short* __restrict__ Bt,   // wbT  [256][2304]
    float* __restrict__ out,                 // [M][256]
    const float* __restrict__ bias,          // [256]
    int M)
{
    __shared__ char lds[4 * 32768];          // A0 | A1 | B0 | B1 (each 256x64 bf16)
    char* Ab0 = lds;
    char* Ab1 = lds + 32768;
    char* Bb0 = lds + 65536;
    char* Bb1 = lds + 98304;

    const int tid  = threadIdx.x;
    const int lane = tid & 63;
    const int wid  = tid >> 6;           // 0..7
    const int wm   = (wid >> 1) * 64;    // 0/64/128/192
    const int wn   = (wid & 1) * 128;    // 0/128
    const int m0   = blockIdx.x * BM;

    f32x4 acc[4][8] = {};

    auto stageA = [&](int chunk, char* dst) {
        #pragma unroll
        for (int it = 0; it < 4; ++it) {
            int o   = it * 8192 + tid * 16;
            int r   = o >> 7;                       // row 0..255
            int scb = (o & 127) ^ ((r & 7) << 4);   // pre-swizzled source col byte
            int ga  = m0 + r; if (ga >= M) ga = M - 1;
            GLOAD_LDS16((const char*)A + (size_t)ga * 4608 + (size_t)chunk * 128 + scb, dst + o);
        }
    };
    auto stageB = [&](int chunk, char* dst) {
        #pragma unroll
        for (int it = 0; it < 4; ++it) {
            int o   = it * 8192 + tid * 16;
            int r   = o >> 7;                       // row 0..255
            int scb = (o & 127) ^ ((r & 7) << 4);
            GLOAD_LDS16((const char*)Bt + (size_t)r * 4608 + (size_t)chunk * 128 + scb, dst + o);
        }
    };

    // prologue: chunks 0 and 1 in flight; wait chunk 0 (8 outstanding = chunk 1)
    stageA(0, Ab0); stageB(0, Bb0);
    stageA(1, Ab1); stageB(1, Bb1);
    asm volatile("s_waitcnt vmcnt(8)" ::: "memory");
    __builtin_amdgcn_s_barrier();
    __builtin_amdgcn_sched_barrier(0);

    for (int t = 0; t < NCH; ++t) {
        const char* Ac = (t & 1) ? Ab1 : Ab0;
        const char* Bc = (t & 1) ? Bb1 : Bb0;
        #pragma unroll
        for (int kk = 0; kk < 2; ++kk) {
            const int koff = kk * 32 + (lane >> 4) * 8;
            bf16x8 af[4], bfr[8];
            #pragma unroll
            for (int i = 0; i < 4; ++i) {
                int ar = wm + i * 16 + (lane & 15);
                af[i] = *(const bf16x8*)(Ac + ((ar * 128 + koff * 2) ^ ((ar & 7) << 4)));
            }
            #pragma unroll
            for (int j = 0; j < 8; ++j) {
                int br = wn + j * 16 + (lane & 15);
                bfr[j] = *(const bf16x8*)(Bc + ((br * 128 + koff * 2) ^ ((br & 7) << 4)));
            }
            #pragma unroll
            for (int i = 0; i < 4; ++i)
                #pragma unroll
                for (int j = 0; j < 8; ++j)
                    acc[i][j] = __builtin_amdgcn_mfma_f32_16x16x32_bf16(af[i], bfr[j], acc[i][j], 0, 0, 0);
        }

        if (t < NCH - 1) {
            __builtin_amdgcn_s_barrier();          // all waves done reading buf[t&1]
            __builtin_amdgcn_sched_barrier(0);
            int tn = (t + 2 < NCH) ? t + 2 : NCH - 1;   // clamp (dup goes to dead buffer)
            stageA(tn, (t & 1) ? Ab1 : Ab0);
            stageB(tn, (t & 1) ? Bb1 : Bb0);
            asm volatile("s_waitcnt vmcnt(8)" ::: "memory");  // chunk t+1 ready
            __builtin_amdgcn_s_barrier();
            __builtin_amdgcn_sched_barrier(0);
        }
    }
    asm volatile("s_waitcnt vmcnt(0)" ::: "memory");   // drain clamp-issued extras

    // D mapping: col=lane&15, row=(lane>>4)*4+reg
    const int col = lane & 15;
    const int r0  = (lane >> 4) * 4;
    #pragma unroll
    for (int i = 0; i < 4; ++i) {
        #pragma unroll
        for (int j = 0; j < 8; ++j) {
            int gn = wn + j * 16 + col;
            float bv = bias[gn];
            #pragma unroll
            for (int rr = 0; rr < 4; ++rr) {
                int gm = m0 + wm + i * 16 + r0 + rr;
                if (gm < M) out[(size_t)gm * 256 + gn] = acc[i][j][rr] + bv;
            }
        }
    }
}

// ---------------------------------------------------------------- launch
extern "C" void kernel_launch(void* const* d_in, const int* in_sizes, int n_in,
                              void* d_out, int out_size, void* d_ws, size_t ws_size,
                              hipStream_t stream) {
    const int*   edge_index = (const int*)d_in[0];   // [2][E]
    const float* x          = (const float*)d_in[1]; // [M][256]
    const int*   edge_type  = (const int*)d_in[2];   // [E]
    const float* weight     = (const float*)d_in[3]; // [8][256][256]
    const float* h_bias     = (const float*)d_in[4]; // [256]
    const float* loop_w     = (const float*)d_in[5]; // [256][256]
    float* out = (float*)d_out;

    const int M = in_sizes[1] / 256;   // 50000
    const int E = in_sizes[2];         // 800000

    // workspace: Zcat 230.4MB | wbT 1.18MB | [cnt M | done | pad | bsum 64] | off M+1 | cur M | recs E
    char* ws = (char*)d_ws;
    size_t off_b = 0;
    unsigned short* Zcat = (unsigned short*)(ws + off_b);
    off_b += (((size_t)M * 2304 * 2) + 255) & ~(size_t)255;
    unsigned short* wbT = (unsigned short*)(ws + off_b);
    off_b += (((size_t)256 * 2304 * 2) + 255) & ~(size_t)255;
    unsigned* cnt = (unsigned*)(ws + off_b);            // cnt[M], done, pad, bsum[64]
    unsigned* done = cnt + M;
    unsigned* bsum = cnt + M + 2;
    off_b += (((size_t)(M + 2 + 64) * 4) + 255) & ~(size_t)255;
    unsigned* off = (unsigned*)(ws + off_b);
    off_b += (((size_t)(M + 1) * 4) + 255) & ~(size_t)255;
    unsigned* cur = (unsigned*)(ws + off_b);
    off_b += (((size_t)M * 4) + 255) & ~(size_t)255;
    unsigned* recs = (unsigned*)(ws + off_b);

    const int nb = (M + 1023) / 1024;   // 49 scan blocks (all co-resident)
    const int HB = (E + 255) / 256;     // 3125
    const int CB = (M + 3) / 4;         // 12500

    // zero cnt + done + bsum in one async memset (capture-safe)
    (void)hipMemsetAsync(cnt, 0, (size_t)(M + 2 + 64) * 4, stream);

    // fused: histogram + bf16-x + weight transpose (independent work)
    rgcn_prep<<<HB + CB + 2304, 256, 0, stream>>>(edge_index, cnt, x, Zcat,
                                                  weight, loop_w, wbT, E, M, HB, CB);
    // single-kernel hierarchical scan (replaces scan1+scan2+scan3)
    rgcn_scan_all<<<nb, 1024, 0, stream>>>(cnt, off, cur, done, bsum, M, nb);
    rgcn_scatter<<<(E + 255) / 256, 256, 0, stream>>>(edge_index, edge_type, cur, recs, E);

    // per-dst register aggregation -> Zcat[:, 0:2048]
    rgcn_agg<<<2560, 256, 0, stream>>>(recs, off, Zcat, M);

    // single fused GEMM -> out (256x256 tile, 8 waves, dbuf pipeline)
    rgcn_gemm<<<(M + BM - 1) / BM, 512, 0, stream>>>(Zcat, wbT, out, h_bias, M);
}